// Round 11
// baseline (4010.294 us; speedup 1.0000x reference)
//
#include <hip/hip_runtime.h>

#define BATCH   512
#define TSTEPS  50
#define NIN     784
#define NHID    800
#define NOUT    10
#define KC      384   // OpenBLAS SGEMM_DEFAULT_Q — panel folds at k=384, 768
#define GRP     8     // rows per spmm block

#define BM 128
#define BN 64
#define BK 8

typedef float v4f __attribute__((ext_vector_type(4)));

// ---------------------------------------------------------------------------
// Dense f32 GEMM (NT), OpenBLAS-rounding-exact (layer 1).
// 128x64 tile, 8x4 micro, BK=8. A staged in LDS (k-major); B read DIRECTLY
// from L2 (4 rows x 8 ks per thread, half-chunk register double-buffer) —
// removes 1/3 of LDS reads and B stage writes (LDS-port was the binding
// constraint: 1.5 B/FMA-lane demand vs ~85-128 B/cy supply).
// Plain launch_bounds (no 2nd arg — (256,4) caps VGPR at 64 and spills).
// Per element: ascending-k FMA chain per KC-panel; C = ((P1+P2)+P3).
// Requires M%128==0, K%8==0.
// ---------------------------------------------------------------------------
__global__ __launch_bounds__(256)
void gemm_nt_f32(const float* __restrict__ A, const float* __restrict__ B,
                 float* __restrict__ C, int M, int N, int K)
{
    __shared__ float As[BK][BM + 4];   // [k][m], 8 x 132 (A only)

    const int tid = threadIdx.x;
    const int tx = tid & 15;        // n micro: cols 4*tx .. 4*tx+3
    const int ty = tid >> 4;        // m micro: rows 8*ty .. 8*ty+7

    // bijective XCD swizzle on m-blocks (contiguous m-range per XCD)
    int bx = blockIdx.x;
    const int nbx = gridDim.x;
    if ((nbx & 7) == 0) { const int q = nbx >> 3; bx = (bx & 7) * q + (bx >> 3); }
    const int m0 = bx * BM;
    const int n0 = blockIdx.y * BN;

    const int arow = tid >> 1;          // 0..127
    const int akq  = (tid & 1) * 4;     // 0 or 4
    const float* Aptr = A + (size_t)(m0 + arow) * K + akq;

    // B: this thread's 4 output columns -> 4 B rows
    const float* Bp[4];
    bool bval[4];
    #pragma unroll
    for (int j = 0; j < 4; ++j) {
        const int br = n0 + 4 * tx + j;
        bval[j] = (br < N);
        Bp[j] = B + (size_t)(bval[j] ? br : 0) * K;
    }
    const float4 zero4 = make_float4(0.f, 0.f, 0.f, 0.f);

    float part[8][4];   // current KC-panel chain
    float acc[8][4];    // folded closed panels
    #pragma unroll
    for (int i = 0; i < 8; ++i)
        #pragma unroll
        for (int j = 0; j < 4; ++j) part[i][j] = 0.0f;

    // prologue: A chunk0 + B chunk0 (lo+hi)
    float4 av = *(const float4*)(Aptr);
    float4 blo[4], bhi[4];
    #pragma unroll
    for (int j = 0; j < 4; ++j) {
        blo[j] = bval[j] ? *(const float4*)(Bp[j])     : zero4;
        bhi[j] = bval[j] ? *(const float4*)(Bp[j] + 4) : zero4;
    }

    for (int k0 = 0; k0 < K; k0 += BK) {
        __syncthreads();
        As[akq+0][arow] = av.x; As[akq+1][arow] = av.y;
        As[akq+2][arow] = av.z; As[akq+3][arow] = av.w;
        __syncthreads();

        const bool more = (k0 + BK < K);
        float4 avn, bln[4];
        if (more) {
            avn = *(const float4*)(Aptr + k0 + BK);
            #pragma unroll
            for (int j = 0; j < 4; ++j)
                bln[j] = bval[j] ? *(const float4*)(Bp[j] + k0 + BK) : zero4;
        }

        // KC-panel fold (uniform branch; k0 in {384, 768})
        if (k0 == 384 || k0 == 768) {
            #pragma unroll
            for (int i = 0; i < 8; ++i)
                #pragma unroll
                for (int j = 0; j < 4; ++j) {
                    acc[i][j] = (k0 == 384) ? part[i][j]
                                            : __fadd_rn(acc[i][j], part[i][j]);
                    part[i][j] = 0.0f;
                }
        }

        // kk = 0..3 from blo
        #pragma unroll
        for (int kk = 0; kk < 4; ++kk) {
            float a[8], b[4];
            *(float4*)&a[0] = *(const float4*)&As[kk][8*ty];
            *(float4*)&a[4] = *(const float4*)&As[kk][8*ty + 4];
            #pragma unroll
            for (int j = 0; j < 4; ++j)
                b[j] = (kk==0)? blo[j].x : (kk==1)? blo[j].y
                     : (kk==2)? blo[j].z : blo[j].w;
            #pragma unroll
            for (int i = 0; i < 8; ++i)
                #pragma unroll
                for (int j = 0; j < 4; ++j)
                    part[i][j] = __fmaf_rn(a[i], b[j], part[i][j]);
        }

        // prefetch next-chunk hi while kk=4..7 compute
        float4 bhn[4];
        if (more) {
            #pragma unroll
            for (int j = 0; j < 4; ++j)
                bhn[j] = bval[j] ? *(const float4*)(Bp[j] + k0 + BK + 4) : zero4;
        }

        // kk = 4..7 from bhi
        #pragma unroll
        for (int kk = 4; kk < 8; ++kk) {
            float a[8], b[4];
            *(float4*)&a[0] = *(const float4*)&As[kk][8*ty];
            *(float4*)&a[4] = *(const float4*)&As[kk][8*ty + 4];
            #pragma unroll
            for (int j = 0; j < 4; ++j)
                b[j] = (kk==4)? bhi[j].x : (kk==5)? bhi[j].y
                     : (kk==6)? bhi[j].z : bhi[j].w;
            #pragma unroll
            for (int i = 0; i < 8; ++i)
                #pragma unroll
                for (int j = 0; j < 4; ++j)
                    part[i][j] = __fmaf_rn(a[i], b[j], part[i][j]);
        }

        if (more) {
            av = avn;
            #pragma unroll
            for (int j = 0; j < 4; ++j) { blo[j] = bln[j]; bhi[j] = bhn[j]; }
        }
    }

    #pragma unroll
    for (int i = 0; i < 8; ++i)
        #pragma unroll
        for (int j = 0; j < 4; ++j)
            acc[i][j] = (K <= KC) ? part[i][j] : __fadd_rn(acc[i][j], part[i][j]);

    const int cb = n0 + 4*tx;
    #pragma unroll
    for (int i = 0; i < 8; ++i) {
        const int m = m0 + 8*ty + i;
        float* crow = C + (size_t)m * N + cb;
        if (cb + 3 < N) {
            v4f o = { acc[i][0], acc[i][1], acc[i][2], acc[i][3] };
            __builtin_nontemporal_store(o, (v4f*)crow);
        } else {
            #pragma unroll
            for (int j = 0; j < 4; ++j)
                if (cb + j < N) __builtin_nontemporal_store(acc[i][j], crow + j);
        }
    }
}

// ---------------------------------------------------------------------------
// 800x800 transpose: W2T[k][n] = W2[n][k]
// ---------------------------------------------------------------------------
__global__ __launch_bounds__(256)
void transpose800(const float* __restrict__ W2, float* __restrict__ W2T)
{
    __shared__ float t[32][33];
    const int tx  = threadIdx.x & 31;
    const int ty8 = threadIdx.x >> 5;
    const int bx = blockIdx.x * 32, by = blockIdx.y * 32;

    #pragma unroll
    for (int r = 0; r < 4; ++r) {
        int a = ty8 + r * 8;
        t[a][tx] = W2[(size_t)(by + a) * 800 + bx + tx];
    }
    __syncthreads();
    #pragma unroll
    for (int r = 0; r < 4; ++r) {
        int a = ty8 + r * 8;
        W2T[(size_t)(bx + a) * 800 + by + tx] = t[tx][a];
    }
}

// ---------------------------------------------------------------------------
// LIF scan for hidden layers (Nn=800), block per batch row, emits bitmask.
// Z reads / Sout writes are nontemporal (streaming; protect L2 for weights).
// ---------------------------------------------------------------------------
__global__ __launch_bounds__(256)
void lif_scan_hid(const float* __restrict__ Z,
                  const float* __restrict__ bias,
                  const float* __restrict__ budget,
                  float* __restrict__ mcarry,
                  float* __restrict__ Sout,
                  unsigned long long* __restrict__ bm,
                  int CT, int t0)
{
    const int b = blockIdx.x;
    const int tid = threadIdx.x;
    const int lane = tid & 63;
    const int wave = tid >> 6;

    float m[4], thr[4], bj[4];
    bool val[4];
    #pragma unroll
    for (int c = 0; c < 4; ++c) {
        const int j = c * 256 + tid;
        val[c] = (j < NHID);
        const int jj = val[c] ? j : 0;
        float bu = budget[jj];
        bu = fminf(fmaxf(bu, 0.01f), 1.0f);
        thr[c] = __fdiv_rn(1.0f, bu);
        bj[c]  = bias[jj];
        m[c]   = mcarry[b * NHID + jj];
    }

    for (int ct = 0; ct < CT; ++ct) {
        const size_t zbase = (size_t)ct * (BATCH * NHID) + (size_t)b * NHID;
        const size_t sbase = (size_t)(t0 + ct) * (BATCH * NHID) + (size_t)b * NHID;
        #pragma unroll
        for (int c = 0; c < 4; ++c) {
            const int j = c * 256 + tid;
            bool sp = false;
            if (val[c]) {
                float z = __builtin_nontemporal_load(Z + zbase + j);
                float mm = __fadd_rn(__fadd_rn(__fmul_rn(0.95f, m[c]), z), bj[c]);
                sp = (mm > thr[c]);
                m[c] = sp ? 0.0f : mm;
                __builtin_nontemporal_store(sp ? 1.0f : 0.0f, Sout + sbase + j);
            }
            unsigned long long bits = __ballot(sp);
            if (bm && lane == 0) {
                const int W = c * 4 + wave;
                if (W < 13)
                    bm[((size_t)ct * BATCH + b) * 13 + W] = bits;
            }
        }
    }
    #pragma unroll
    for (int c = 0; c < 4; ++c)
        if (val[c]) mcarry[b * NHID + c * 256 + tid] = m[c];
}

// ---------------------------------------------------------------------------
// Sparse spike GEMM, 8 rows/block, SGPR masks, rotated depth-1 prefetch of
// W2T rows, nontemporal Z stores (keep W2T L2-resident).
// Bit-exact: fma(0,w,p)=p, fma(1,w,p)=fadd(p,w); p never -0 in these chains.
// Panel folds at window boundaries (384=6*64, 768=12*64).
// ---------------------------------------------------------------------------
__global__ __launch_bounds__(256)
void spmm_spikes(const unsigned long long* __restrict__ bm, // [rows][13]
                 const float* __restrict__ W2T,             // [800][800]
                 float* __restrict__ Z,                     // [rows][800]
                 int rows)
{
    const int tid = threadIdx.x;
    const int row0 = blockIdx.x * GRP;
    const bool act = (tid < 200);
    const int n = 4 * (act ? tid : 0);

    float part[GRP][4], acc[GRP][4];
    #pragma unroll
    for (int r = 0; r < GRP; ++r)
        #pragma unroll
        for (int j = 0; j < 4; ++j) { part[r][j] = 0.0f; acc[r][j] = 0.0f; }

    int p = 0;
    for (int w = 0; w < 13; ++w) {
        // close panel at k=384 / k=768 (window-aligned)
        if (w == 6 || w == 12) {
            #pragma unroll
            for (int r = 0; r < GRP; ++r)
                #pragma unroll
                for (int j = 0; j < 4; ++j) {
                    acc[r][j] = (p == 0) ? part[r][j]
                                         : __fadd_rn(acc[r][j], part[r][j]);
                    part[r][j] = 0.0f;
                }
            ++p;
        }

        // masks for this window -> SGPRs
        unsigned long long rm[GRP];
        unsigned long long u = 0ull;
        #pragma unroll
        for (int r = 0; r < GRP; ++r) {
            const unsigned long long v = bm[(size_t)(row0 + r) * 13 + w];
            const unsigned lo = __builtin_amdgcn_readfirstlane((unsigned)v);
            const unsigned hi = __builtin_amdgcn_readfirstlane((unsigned)(v >> 32));
            rm[r] = ((unsigned long long)hi << 32) | lo;
            u |= rm[r];
        }
        if (!u) continue;

        // rotated walk: load k_{i+1} before FMAs of k_i
        int b0 = __builtin_ctzll(u);
        u &= u - 1ull;
        float4 wq = *(const float4*)(W2T + (size_t)((w << 6) + b0) * NHID + n);

        while (u) {
            const int b1 = __builtin_ctzll(u);
            u &= u - 1ull;
            const float4 wq1 =
                *(const float4*)(W2T + (size_t)((w << 6) + b1) * NHID + n);
            #pragma unroll
            for (int r = 0; r < GRP; ++r) {
                const float mf = ((rm[r] >> b0) & 1ull) ? 1.0f : 0.0f;
                part[r][0] = __fmaf_rn(mf, wq.x, part[r][0]);
                part[r][1] = __fmaf_rn(mf, wq.y, part[r][1]);
                part[r][2] = __fmaf_rn(mf, wq.z, part[r][2]);
                part[r][3] = __fmaf_rn(mf, wq.w, part[r][3]);
            }
            b0 = b1; wq = wq1;
        }
        #pragma unroll
        for (int r = 0; r < GRP; ++r) {
            const float mf = ((rm[r] >> b0) & 1ull) ? 1.0f : 0.0f;
            part[r][0] = __fmaf_rn(mf, wq.x, part[r][0]);
            part[r][1] = __fmaf_rn(mf, wq.y, part[r][1]);
            part[r][2] = __fmaf_rn(mf, wq.z, part[r][2]);
            part[r][3] = __fmaf_rn(mf, wq.w, part[r][3]);
        }
    }
    // close last panel (p==2 here for K=800)
    #pragma unroll
    for (int r = 0; r < GRP; ++r)
        #pragma unroll
        for (int j = 0; j < 4; ++j)
            acc[r][j] = (p == 0) ? part[r][j]
                                 : __fadd_rn(acc[r][j], part[r][j]);

    if (act) {
        #pragma unroll
        for (int r = 0; r < GRP; ++r) {
            v4f o = { acc[r][0], acc[r][1], acc[r][2], acc[r][3] };
            __builtin_nontemporal_store(o, (v4f*)(Z + (size_t)(row0 + r) * NHID + n));
        }
    }
}

// ---------------------------------------------------------------------------
// Layer-3 GEMM, float4 loads (4x fewer VMEM instrs), chain preserved:
// per element ascending-k scalar FMA; folds at float4 index 96 (k=384) and
// 192 (k=768).
// ---------------------------------------------------------------------------
__global__ __launch_bounds__(256)
void gemm3_f32(const float* __restrict__ S2, const float* __restrict__ W3,
               float* __restrict__ Z3, int rows)
{
    int gid = blockIdx.x * 256 + threadIdx.x;
    if (gid >= rows * NOUT) return;
    const int m = gid / NOUT;
    const int nn = gid % NOUT;
    const float* a = S2 + (size_t)m * NHID;
    const float* wr = W3 + (size_t)nn * NHID;

    float part = 0.0f, acc = 0.0f;
    int p = 0;
    for (int i = 0; i < NHID / 4; ++i) {
        if (i == 96 || i == 192) {
            acc = (p == 0) ? part : __fadd_rn(acc, part);
            part = 0.0f; ++p;
        }
        const v4f a4 = __builtin_nontemporal_load((const v4f*)(a + 4 * i));
        const float4 w4 = *(const float4*)(wr + 4 * i);
        part = __fmaf_rn(a4.x, w4.x, part);
        part = __fmaf_rn(a4.y, w4.y, part);
        part = __fmaf_rn(a4.z, w4.z, part);
        part = __fmaf_rn(a4.w, w4.w, part);
    }
    acc = (p == 0) ? part : __fadd_rn(acc, part);
    Z3[gid] = acc;
}

// ---------------------------------------------------------------------------
__global__ __launch_bounds__(256)
void lif_scan_small(const float* __restrict__ Z, const float* __restrict__ bias,
                    float* __restrict__ mcarry, float* __restrict__ Sout,
                    int CT, int t0)
{
    const int idx = blockIdx.x * blockDim.x + threadIdx.x;
    const int total = BATCH * NOUT;
    if (idx >= total) return;
    const int j = idx % NOUT;
    const float thr = 1.0f;
    const float bj = bias[j];

    float m = mcarry[idx];
    for (int ct = 0; ct < CT; ++ct) {
        float z = Z[(size_t)ct * total + idx];
        m = __fadd_rn(__fadd_rn(__fmul_rn(0.95f, m), z), bj);
        float s;
        if (m > thr) { s = 1.0f; m = 0.0f; }
        else         { s = 0.0f; }
        Sout[(size_t)(t0 + ct) * total + idx] = s;
    }
    mcarry[idx] = m;
}

// ---------------------------------------------------------------------------
__global__ __launch_bounds__(256)
void sum_t(const float* __restrict__ S3, float* __restrict__ out0)
{
    const int idx = blockIdx.x * blockDim.x + threadIdx.x;
    if (idx >= BATCH * NOUT) return;
    float s = 0.0f;
    for (int t = 0; t < TSTEPS; ++t)
        s += S3[(size_t)t * BATCH * NOUT + idx];
    out0[idx] = s;
}

// ---------------------------------------------------------------------------
extern "C" void kernel_launch(void* const* d_in, const int* in_sizes, int n_in,
                              void* d_out, int out_size, void* d_ws, size_t ws_size,
                              hipStream_t stream)
{
    const float* x       = (const float*)d_in[0];
    const float* W1      = (const float*)d_in[1];
    const float* b1      = (const float*)d_in[2];
    const float* W2      = (const float*)d_in[3];
    const float* b2      = (const float*)d_in[4];
    const float* W3      = (const float*)d_in[5];
    const float* b3      = (const float*)d_in[6];
    const float* budget1 = (const float*)d_in[7];
    const float* budget2 = (const float*)d_in[8];

    float* out  = (float*)d_out;
    float* out0 = out;
    float* out1 = out0 + BATCH * NOUT;
    float* out2 = out1 + (size_t)TSTEPS * BATCH * NHID;
    float* out3 = out2 + (size_t)TSTEPS * BATCH * NHID;

    const size_t nBH = (size_t)BATCH * NHID;
    const size_t nBO = (size_t)BATCH * NOUT;
    float* m1c = (float*)d_ws;
    float* m2c = m1c + nBH;
    float* m3c = m2c + nBH;
    float* w2t = m3c + nBO;
    unsigned long long* bmask = (unsigned long long*)(w2t + (size_t)NHID * NHID);
    float* Z = (float*)(bmask + (size_t)TSTEPS * BATCH * 13);

    const size_t fixedF = 2 * nBH + nBO + (size_t)NHID * NHID
                        + (size_t)TSTEPS * BATCH * 13 * 2;
    size_t availF = (ws_size / 4 > fixedF) ? (ws_size / 4 - fixedF) : 0;
    const size_t perT = (size_t)BATCH * (NHID + NOUT);
    int CT = (int)(availF / perT);
    if (CT > TSTEPS) CT = TSTEPS;
    if (CT < 1) CT = 1;

    hipMemsetAsync(d_ws, 0, (2 * nBH + nBO) * sizeof(float), stream);

    {
        dim3 tg(25, 25);
        transpose800<<<tg, 256, 0, stream>>>(W2, w2t);
    }

    for (int t0 = 0; t0 < TSTEPS; t0 += CT) {
        int ct = TSTEPS - t0 < CT ? TSTEPS - t0 : CT;
        int Mrows = ct * BATCH;
        float* Z3 = Z + (size_t)ct * BATCH * NHID;

        // layer 1: dense Z = x_chunk @ W1^T
        {
            dim3 grid(Mrows / BM, (NHID + BN - 1) / BN);
            gemm_nt_f32<<<grid, 256, 0, stream>>>(
                x + (size_t)t0 * BATCH * NIN, W1, Z, Mrows, NHID, NIN);
        }
        lif_scan_hid<<<BATCH, 256, 0, stream>>>(
            Z, b1, budget1, m1c, out1, bmask, ct, t0);

        // layer 2: sparse Z = s1_chunk @ W2^T via SGPR masks
        spmm_spikes<<<Mrows / GRP, 256, 0, stream>>>(bmask, w2t, Z, Mrows);
        lif_scan_hid<<<BATCH, 256, 0, stream>>>(
            Z, b2, budget2, m2c, out2, nullptr, ct, t0);

        // layer 3
        gemm3_f32<<<(Mrows * NOUT + 255) / 256, 256, 0, stream>>>(
            out2 + (size_t)t0 * BATCH * NHID, W3, Z3, Mrows);
        lif_scan_small<<<(BATCH * NOUT + 255) / 256, 256, 0, stream>>>(
            Z3, b3, m3c, out3, ct, t0);
    }

    sum_t<<<(BATCH * NOUT + 255) / 256, 256, 0, stream>>>(out3, out0);
}

// Round 12
// 1006.979 us; speedup vs baseline: 3.9825x; 3.9825x over previous
//
#include <hip/hip_runtime.h>

#define BATCH   512
#define TSTEPS  50
#define NIN     784
#define NHID    800
#define NOUT    10
#define KC      384   // OpenBLAS SGEMM_DEFAULT_Q — panel folds at k=384, 768

typedef float v4f __attribute__((ext_vector_type(4)));

// ---------------------------------------------------------------------------
// Panel GEMM (NT): computes ONE KC-panel's ascending-k FMA chain:
//   Cp[m,n] = chain_{k=ks..ke-1} fma(A[m,k], B[n,k], .) from 0.
// The cross-panel fold ((P1+P2)+P3) happens in lif_scan_hid (bit-exact
// OpenBLAS combine). Single part[8][8] accumulator -> no part/acc split.
// 128x128 tile, 8x8 micro, BK=8, k-major LDS, swizzled B (2-way, free).
// Plain launch_bounds: (256,4) would cap VGPR at 64 and spill (round 7).
// Requires M%128==0, (ke-ks)%8==0.
// ---------------------------------------------------------------------------
__global__ __launch_bounds__(256)
void gemm_panel_f32(const float* __restrict__ A, const float* __restrict__ B,
                    float* __restrict__ Cp, int M, int N, int K,
                    int ks, int ke)
{
    __shared__ float As[8][132];   // [k][m]
    __shared__ float Bs[8][188];   // [k][phys(n)], phys = 12*(n>>3)+(n&7)

    const int tid = threadIdx.x;
    const int tx = tid & 15;        // n micro: 8 cols at 8*tx
    const int ty = tid >> 4;        // m micro: 8 rows at 8*ty
    const int m0 = blockIdx.x * 128;
    const int n0 = blockIdx.y * 128;

    const int srow = tid >> 1;          // 0..127
    const int skq  = (tid & 1) * 4;     // 0 or 4
    const int bphys = 12 * (srow >> 3) + (srow & 7);

    const float* Aptr = A + (size_t)(m0 + srow) * K + skq;
    const float* Bptr = B + (size_t)(n0 + srow) * K + skq;
    const bool bval = (n0 + srow) < N;

    float part[8][8];
    #pragma unroll
    for (int i = 0; i < 8; ++i)
        #pragma unroll
        for (int j = 0; j < 8; ++j) part[i][j] = 0.0f;

    float4 av = *(const float4*)(Aptr + ks);
    float4 bv = bval ? *(const float4*)(Bptr + ks) : make_float4(0.f,0.f,0.f,0.f);

    for (int k0 = ks; k0 < ke; k0 += 8) {
        __syncthreads();
        As[skq+0][srow] = av.x; As[skq+1][srow] = av.y;
        As[skq+2][srow] = av.z; As[skq+3][srow] = av.w;
        Bs[skq+0][bphys] = bv.x; Bs[skq+1][bphys] = bv.y;
        Bs[skq+2][bphys] = bv.z; Bs[skq+3][bphys] = bv.w;
        __syncthreads();

        if (k0 + 8 < ke) {
            av = *(const float4*)(Aptr + k0 + 8);
            bv = bval ? *(const float4*)(Bptr + k0 + 8)
                      : make_float4(0.f,0.f,0.f,0.f);
        }

        #pragma unroll
        for (int kk = 0; kk < 8; ++kk) {
            float a[8], b[8];
            *(float4*)&a[0] = *(const float4*)&As[kk][8*ty];
            *(float4*)&a[4] = *(const float4*)&As[kk][8*ty + 4];
            *(float4*)&b[0] = *(const float4*)&Bs[kk][12*tx];
            *(float4*)&b[4] = *(const float4*)&Bs[kk][12*tx + 4];
            #pragma unroll
            for (int i = 0; i < 8; ++i)
                #pragma unroll
                for (int j = 0; j < 8; ++j)
                    part[i][j] = __fmaf_rn(a[i], b[j], part[i][j]);
        }
    }

    const int cb = n0 + 8 * tx;
    #pragma unroll
    for (int i = 0; i < 8; ++i) {
        float* crow = Cp + (size_t)(m0 + 8*ty + i) * N + cb;
        if (cb + 4 <= N) {
            v4f o = { part[i][0], part[i][1], part[i][2], part[i][3] };
            __builtin_nontemporal_store(o, (v4f*)crow);
        }
        if (cb + 8 <= N) {
            v4f o = { part[i][4], part[i][5], part[i][6], part[i][7] };
            __builtin_nontemporal_store(o, (v4f*)(crow + 4));
        }
    }
}

// ---------------------------------------------------------------------------
// 800x800 transpose: W2T[k][n] = W2[n][k]
// ---------------------------------------------------------------------------
__global__ __launch_bounds__(256)
void transpose800(const float* __restrict__ W2, float* __restrict__ W2T)
{
    __shared__ float t[32][33];
    const int tx  = threadIdx.x & 31;
    const int ty8 = threadIdx.x >> 5;
    const int bx = blockIdx.x * 32, by = blockIdx.y * 32;

    #pragma unroll
    for (int r = 0; r < 4; ++r) {
        int a = ty8 + r * 8;
        t[a][tx] = W2[(size_t)(by + a) * 800 + bx + tx];
    }
    __syncthreads();
    #pragma unroll
    for (int r = 0; r < 4; ++r) {
        int a = ty8 + r * 8;
        W2T[(size_t)(bx + a) * 800 + by + tx] = t[tx][a];
    }
}

// ---------------------------------------------------------------------------
// LIF scan for hidden layers (Nn=800), block per batch row, emits bitmask.
// np panels: z = ((P1+P2)+P3) f32 adds in panel order — the exact OpenBLAS
// cross-panel combine. m = ((0.95f*m) + z) + b[j]; s = (m > thr); mult reset.
// ---------------------------------------------------------------------------
__global__ __launch_bounds__(256)
void lif_scan_hid(const float* __restrict__ Z0,
                  const float* __restrict__ Z1,   // may be null
                  const float* __restrict__ Z2,   // may be null
                  int np,
                  const float* __restrict__ bias,
                  const float* __restrict__ budget,
                  float* __restrict__ mcarry,
                  float* __restrict__ Sout,
                  unsigned long long* __restrict__ bm,
                  int CT, int t0)
{
    const int b = blockIdx.x;
    const int tid = threadIdx.x;
    const int lane = tid & 63;
    const int wave = tid >> 6;

    float m[4], thr[4], bj[4];
    bool val[4];
    #pragma unroll
    for (int c = 0; c < 4; ++c) {
        const int j = c * 256 + tid;
        val[c] = (j < NHID);
        const int jj = val[c] ? j : 0;
        float bu = budget[jj];
        bu = fminf(fmaxf(bu, 0.01f), 1.0f);
        thr[c] = __fdiv_rn(1.0f, bu);
        bj[c]  = bias[jj];
        m[c]   = mcarry[b * NHID + jj];
    }

    for (int ct = 0; ct < CT; ++ct) {
        const size_t zbase = (size_t)ct * (BATCH * NHID) + (size_t)b * NHID;
        const size_t sbase = (size_t)(t0 + ct) * (BATCH * NHID) + (size_t)b * NHID;
        #pragma unroll
        for (int c = 0; c < 4; ++c) {
            const int j = c * 256 + tid;
            bool sp = false;
            if (val[c]) {
                float z = __builtin_nontemporal_load(Z0 + zbase + j);
                if (np >= 2)
                    z = __fadd_rn(z, __builtin_nontemporal_load(Z1 + zbase + j));
                if (np >= 3)
                    z = __fadd_rn(z, __builtin_nontemporal_load(Z2 + zbase + j));
                float mm = __fadd_rn(__fadd_rn(__fmul_rn(0.95f, m[c]), z), bj[c]);
                sp = (mm > thr[c]);
                m[c] = sp ? 0.0f : mm;
                __builtin_nontemporal_store(sp ? 1.0f : 0.0f, Sout + sbase + j);
            }
            unsigned long long bits = __ballot(sp);
            if (bm && lane == 0) {
                const int W = c * 4 + wave;
                if (W < 13)
                    bm[((size_t)ct * BATCH + b) * 13 + W] = bits;
            }
        }
    }
    #pragma unroll
    for (int c = 0; c < 4; ++c)
        if (val[c]) mcarry[b * NHID + c * 256 + tid] = m[c];
}

// ---------------------------------------------------------------------------
// Sparse spike GEMM — round-6 proven version (~276 us). Block per row;
// bitmask -> ordered k-list in LDS (popcount prefix), wave-uniform walk.
// Bit-exact: active k appends fadd(part, w); panel folds tracked by k index.
// ---------------------------------------------------------------------------
__global__ __launch_bounds__(256)
void spmm_spikes(const unsigned long long* __restrict__ bm, // [rows][13]
                 const float* __restrict__ W2T,             // [800][800]
                 float* __restrict__ Z,                     // [rows][800]
                 int rows)
{
    __shared__ unsigned long long wbuf[13];
    __shared__ unsigned short list[NHID];
    __shared__ int offs[14];

    const int tid = threadIdx.x;
    const int lane = tid & 63;
    const int wave = tid >> 6;
    const int row = blockIdx.x;

    if (tid < 13) wbuf[tid] = bm[(size_t)row * 13 + tid];
    __syncthreads();
    if (tid == 0) {
        int o = 0;
        for (int w = 0; w < 13; ++w) { offs[w] = o; o += __popcll(wbuf[w]); }
        offs[13] = o;
    }
    __syncthreads();
    for (int W = wave; W < 13; W += 4) {
        const unsigned long long bits = wbuf[W];
        const int pre = __popcll(bits & ((1ull << lane) - 1ull));
        if ((bits >> lane) & 1ull)
            list[offs[W] + pre] = (unsigned short)(W * 64 + lane);
    }
    __syncthreads();
    const int nnz = offs[13];

    if (tid < 200) {
        const int n = 4 * tid;
        float p0 = 0.f, p1 = 0.f, p2 = 0.f, p3 = 0.f;
        float a0 = 0.f, a1 = 0.f, a2 = 0.f, a3 = 0.f;
        int p = 0, nextb = KC;          // 384 then 768 then "never"
        for (int i = 0; i < nnz; ++i) {
            const int k = list[i];
            while (k >= nextb) {
                if (p == 0) { a0 = p0; a1 = p1; a2 = p2; a3 = p3; }
                else {
                    a0 = __fadd_rn(a0, p0); a1 = __fadd_rn(a1, p1);
                    a2 = __fadd_rn(a2, p2); a3 = __fadd_rn(a3, p3);
                }
                p0 = p1 = p2 = p3 = 0.f; ++p;
                nextb = (nextb == KC) ? 2 * KC : 100000;
            }
            const float4 w = *(const float4*)(W2T + (size_t)k * NHID + n);
            p0 = __fadd_rn(p0, w.x); p1 = __fadd_rn(p1, w.y);
            p2 = __fadd_rn(p2, w.z); p3 = __fadd_rn(p3, w.w);
        }
        while (p < 3) {                 // close remaining panels (K=800 -> 3)
            if (p == 0) { a0 = p0; a1 = p1; a2 = p2; a3 = p3; }
            else {
                a0 = __fadd_rn(a0, p0); a1 = __fadd_rn(a1, p1);
                a2 = __fadd_rn(a2, p2); a3 = __fadd_rn(a3, p3);
            }
            p0 = p1 = p2 = p3 = 0.f; ++p;
        }
        *(float4*)(Z + (size_t)row * NHID + n) = make_float4(a0, a1, a2, a3);
    }
}

// ---------------------------------------------------------------------------
// Layer-3 GEMM, float4 loads, chain preserved (folds at float4 idx 96/192).
// ---------------------------------------------------------------------------
__global__ __launch_bounds__(256)
void gemm3_f32(const float* __restrict__ S2, const float* __restrict__ W3,
               float* __restrict__ Z3, int rows)
{
    int gid = blockIdx.x * 256 + threadIdx.x;
    if (gid >= rows * NOUT) return;
    const int m = gid / NOUT;
    const int nn = gid % NOUT;
    const float* a = S2 + (size_t)m * NHID;
    const float* wr = W3 + (size_t)nn * NHID;

    float part = 0.0f, acc = 0.0f;
    int p = 0;
    for (int i = 0; i < NHID / 4; ++i) {
        if (i == 96 || i == 192) {
            acc = (p == 0) ? part : __fadd_rn(acc, part);
            part = 0.0f; ++p;
        }
        const v4f a4 = __builtin_nontemporal_load((const v4f*)(a + 4 * i));
        const float4 w4 = *(const float4*)(wr + 4 * i);
        part = __fmaf_rn(a4.x, w4.x, part);
        part = __fmaf_rn(a4.y, w4.y, part);
        part = __fmaf_rn(a4.z, w4.z, part);
        part = __fmaf_rn(a4.w, w4.w, part);
    }
    acc = (p == 0) ? part : __fadd_rn(acc, part);
    Z3[gid] = acc;
}

// ---------------------------------------------------------------------------
__global__ __launch_bounds__(256)
void lif_scan_small(const float* __restrict__ Z, const float* __restrict__ bias,
                    float* __restrict__ mcarry, float* __restrict__ Sout,
                    int CT, int t0)
{
    const int idx = blockIdx.x * blockDim.x + threadIdx.x;
    const int total = BATCH * NOUT;
    if (idx >= total) return;
    const int j = idx % NOUT;
    const float thr = 1.0f;
    const float bj = bias[j];

    float m = mcarry[idx];
    for (int ct = 0; ct < CT; ++ct) {
        float z = Z[(size_t)ct * total + idx];
        m = __fadd_rn(__fadd_rn(__fmul_rn(0.95f, m), z), bj);
        float s;
        if (m > thr) { s = 1.0f; m = 0.0f; }
        else         { s = 0.0f; }
        Sout[(size_t)(t0 + ct) * total + idx] = s;
    }
    mcarry[idx] = m;
}

// ---------------------------------------------------------------------------
__global__ __launch_bounds__(256)
void sum_t(const float* __restrict__ S3, float* __restrict__ out0)
{
    const int idx = blockIdx.x * blockDim.x + threadIdx.x;
    if (idx >= BATCH * NOUT) return;
    float s = 0.0f;
    for (int t = 0; t < TSTEPS; ++t)
        s += S3[(size_t)t * BATCH * NOUT + idx];
    out0[idx] = s;
}

// ---------------------------------------------------------------------------
extern "C" void kernel_launch(void* const* d_in, const int* in_sizes, int n_in,
                              void* d_out, int out_size, void* d_ws, size_t ws_size,
                              hipStream_t stream)
{
    const float* x       = (const float*)d_in[0];
    const float* W1      = (const float*)d_in[1];
    const float* b1      = (const float*)d_in[2];
    const float* W2      = (const float*)d_in[3];
    const float* b2      = (const float*)d_in[4];
    const float* W3      = (const float*)d_in[5];
    const float* b3      = (const float*)d_in[6];
    const float* budget1 = (const float*)d_in[7];
    const float* budget2 = (const float*)d_in[8];

    float* out  = (float*)d_out;
    float* out0 = out;
    float* out1 = out0 + BATCH * NOUT;
    float* out2 = out1 + (size_t)TSTEPS * BATCH * NHID;
    float* out3 = out2 + (size_t)TSTEPS * BATCH * NHID;

    const size_t nBH = (size_t)BATCH * NHID;     // 409600
    const size_t nBO = (size_t)BATCH * NOUT;     // 5120
    float* m1c = (float*)d_ws;
    float* m2c = m1c + nBH;
    float* m3c = m2c + nBH;
    float* w2t = m3c + nBO;
    unsigned long long* bmask = (unsigned long long*)(w2t + (size_t)NHID * NHID);
    float* Z = (float*)(bmask + (size_t)TSTEPS * BATCH * 13);

    const size_t fixedF = 2 * nBH + nBO + (size_t)NHID * NHID
                        + (size_t)TSTEPS * BATCH * 13 * 2;
    size_t availF = (ws_size / 4 > fixedF) ? (ws_size / 4 - fixedF) : 0;
    // per timestep: 3 Z-panels (layer 1) + Z3
    const size_t perT = (size_t)BATCH * (3 * NHID + NOUT);
    int CT = (int)(availF / perT);
    if (CT > TSTEPS) CT = TSTEPS;
    if (CT < 1) CT = 1;

    hipMemsetAsync(d_ws, 0, (2 * nBH + nBO) * sizeof(float), stream);

    {
        dim3 tg(25, 25);
        transpose800<<<tg, 256, 0, stream>>>(W2, w2t);
    }

    for (int t0 = 0; t0 < TSTEPS; t0 += CT) {
        int ct = TSTEPS - t0 < CT ? TSTEPS - t0 : CT;
        int Mrows = ct * BATCH;
        const size_t pstride = (size_t)ct * BATCH * NHID;
        float* Zp0 = Z;
        float* Zp1 = Z + pstride;
        float* Zp2 = Z + 2 * pstride;
        float* Z3  = Z + 3 * pstride;

        // layer 1: three K-panels of x_chunk @ W1^T
        {
            dim3 grid(Mrows / 128, (NHID + 127) / 128);
            const float* xc = x + (size_t)t0 * BATCH * NIN;
            gemm_panel_f32<<<grid, 256, 0, stream>>>(xc, W1, Zp0, Mrows, NHID, NIN, 0,   384);
            gemm_panel_f32<<<grid, 256, 0, stream>>>(xc, W1, Zp1, Mrows, NHID, NIN, 384, 768);
            gemm_panel_f32<<<grid, 256, 0, stream>>>(xc, W1, Zp2, Mrows, NHID, NIN, 768, 784);
        }
        lif_scan_hid<<<BATCH, 256, 0, stream>>>(
            Zp0, Zp1, Zp2, 3, b1, budget1, m1c, out1, bmask, ct, t0);

        // layer 2: sparse Z = s1_chunk @ W2^T via bitmask (1 row/block)
        spmm_spikes<<<Mrows, 256, 0, stream>>>(bmask, w2t, Zp0, Mrows);
        lif_scan_hid<<<BATCH, 256, 0, stream>>>(
            Zp0, nullptr, nullptr, 1, b2, budget2, m2c, out2, nullptr, ct, t0);

        // layer 3
        gemm3_f32<<<(Mrows * NOUT + 255) / 256, 256, 0, stream>>>(
            out2 + (size_t)t0 * BATCH * NHID, W3, Z3, Mrows);
        lif_scan_small<<<(BATCH * NOUT + 255) / 256, 256, 0, stream>>>(
            Z3, b3, m3c, out3, ct, t0);
    }

    sum_t<<<(BATCH * NOUT + 255) / 256, 256, 0, stream>>>(out3, out0);
}

// Round 13
// 1006.236 us; speedup vs baseline: 3.9854x; 1.0007x over previous
//
#include <hip/hip_runtime.h>

#define BATCH   512
#define TSTEPS  50
#define NIN     784
#define NHID    800
#define NOUT    10
#define KC      384   // OpenBLAS SGEMM_DEFAULT_Q — panel folds at k=384, 768

typedef float v4f __attribute__((ext_vector_type(4)));

// ---------------------------------------------------------------------------
// Panel GEMM (NT): computes ONE KC-panel's ascending-k FMA chain:
//   Cp[m,n] = chain_{k=ks..ke-1} fma(A[m,k], B[n,k], .) from 0.
// Cross-panel fold ((P1+P2)+P3) happens in lif_scan_hid (bit-exact OpenBLAS
// combine). Single part[8][8] accumulator.
// 128x128 tile, 8x8 micro, BK=8, k-major LDS, swizzled B.
// __launch_bounds__(256,2): cap ~128 VGPR — fits ~105 live regs, no spill
// (plain (256) let the allocator pick 60 and spill: round-12 counters;
//  (256,4) caps at 64 and force-spills: round-7 catastrophe).
// Requires M%128==0, (ke-ks)%8==0.
// ---------------------------------------------------------------------------
__global__ __launch_bounds__(256, 2)
void gemm_panel_f32(const float* __restrict__ A, const float* __restrict__ B,
                    float* __restrict__ Cp, int M, int N, int K,
                    int ks, int ke)
{
    __shared__ float As[8][132];   // [k][m]
    __shared__ float Bs[8][188];   // [k][phys(n)], phys = 12*(n>>3)+(n&7)

    const int tid = threadIdx.x;
    const int tx = tid & 15;        // n micro: 8 cols at 8*tx
    const int ty = tid >> 4;        // m micro: 8 rows at 8*ty
    const int m0 = blockIdx.x * 128;
    const int n0 = blockIdx.y * 128;

    const int srow = tid >> 1;          // 0..127
    const int skq  = (tid & 1) * 4;     // 0 or 4
    const int bphys = 12 * (srow >> 3) + (srow & 7);

    const float* Aptr = A + (size_t)(m0 + srow) * K + skq;
    const float* Bptr = B + (size_t)(n0 + srow) * K + skq;
    const bool bval = (n0 + srow) < N;

    float part[8][8];
    #pragma unroll
    for (int i = 0; i < 8; ++i)
        #pragma unroll
        for (int j = 0; j < 8; ++j) part[i][j] = 0.0f;

    float4 av = *(const float4*)(Aptr + ks);
    float4 bv = bval ? *(const float4*)(Bptr + ks) : make_float4(0.f,0.f,0.f,0.f);

    for (int k0 = ks; k0 < ke; k0 += 8) {
        __syncthreads();
        As[skq+0][srow] = av.x; As[skq+1][srow] = av.y;
        As[skq+2][srow] = av.z; As[skq+3][srow] = av.w;
        Bs[skq+0][bphys] = bv.x; Bs[skq+1][bphys] = bv.y;
        Bs[skq+2][bphys] = bv.z; Bs[skq+3][bphys] = bv.w;
        __syncthreads();

        if (k0 + 8 < ke) {
            av = *(const float4*)(Aptr + k0 + 8);
            bv = bval ? *(const float4*)(Bptr + k0 + 8)
                      : make_float4(0.f,0.f,0.f,0.f);
        }

        #pragma unroll
        for (int kk = 0; kk < 8; ++kk) {
            float a[8], b[8];
            *(float4*)&a[0] = *(const float4*)&As[kk][8*ty];
            *(float4*)&a[4] = *(const float4*)&As[kk][8*ty + 4];
            *(float4*)&b[0] = *(const float4*)&Bs[kk][12*tx];
            *(float4*)&b[4] = *(const float4*)&Bs[kk][12*tx + 4];
            #pragma unroll
            for (int i = 0; i < 8; ++i)
                #pragma unroll
                for (int j = 0; j < 8; ++j)
                    part[i][j] = __fmaf_rn(a[i], b[j], part[i][j]);
        }
    }

    const int cb = n0 + 8 * tx;
    #pragma unroll
    for (int i = 0; i < 8; ++i) {
        float* crow = Cp + (size_t)(m0 + 8*ty + i) * N + cb;
        if (cb + 4 <= N) {
            v4f o = { part[i][0], part[i][1], part[i][2], part[i][3] };
            __builtin_nontemporal_store(o, (v4f*)crow);
        }
        if (cb + 8 <= N) {
            v4f o = { part[i][4], part[i][5], part[i][6], part[i][7] };
            __builtin_nontemporal_store(o, (v4f*)(crow + 4));
        }
    }
}

// ---------------------------------------------------------------------------
// 800x800 transpose: W2T[k][n] = W2[n][k]
// ---------------------------------------------------------------------------
__global__ __launch_bounds__(256)
void transpose800(const float* __restrict__ W2, float* __restrict__ W2T)
{
    __shared__ float t[32][33];
    const int tx  = threadIdx.x & 31;
    const int ty8 = threadIdx.x >> 5;
    const int bx = blockIdx.x * 32, by = blockIdx.y * 32;

    #pragma unroll
    for (int r = 0; r < 4; ++r) {
        int a = ty8 + r * 8;
        t[a][tx] = W2[(size_t)(by + a) * 800 + bx + tx];
    }
    __syncthreads();
    #pragma unroll
    for (int r = 0; r < 4; ++r) {
        int a = ty8 + r * 8;
        W2T[(size_t)(bx + a) * 800 + by + tx] = t[tx][a];
    }
}

// ---------------------------------------------------------------------------
// LIF scan for hidden layers (Nn=800), block per batch row, emits bitmask.
// np panels: z = ((P1+P2)+P3) f32 adds in panel order — the exact OpenBLAS
// cross-panel combine. m = ((0.95f*m) + z) + b[j]; s = (m > thr); mult reset.
// ---------------------------------------------------------------------------
__global__ __launch_bounds__(256)
void lif_scan_hid(const float* __restrict__ Z0,
                  const float* __restrict__ Z1,   // may be null
                  const float* __restrict__ Z2,   // may be null
                  int np,
                  const float* __restrict__ bias,
                  const float* __restrict__ budget,
                  float* __restrict__ mcarry,
                  float* __restrict__ Sout,
                  unsigned long long* __restrict__ bm,
                  int CT, int t0)
{
    const int b = blockIdx.x;
    const int tid = threadIdx.x;
    const int lane = tid & 63;
    const int wave = tid >> 6;

    float m[4], thr[4], bj[4];
    bool val[4];
    #pragma unroll
    for (int c = 0; c < 4; ++c) {
        const int j = c * 256 + tid;
        val[c] = (j < NHID);
        const int jj = val[c] ? j : 0;
        float bu = budget[jj];
        bu = fminf(fmaxf(bu, 0.01f), 1.0f);
        thr[c] = __fdiv_rn(1.0f, bu);
        bj[c]  = bias[jj];
        m[c]   = mcarry[b * NHID + jj];
    }

    for (int ct = 0; ct < CT; ++ct) {
        const size_t zbase = (size_t)ct * (BATCH * NHID) + (size_t)b * NHID;
        const size_t sbase = (size_t)(t0 + ct) * (BATCH * NHID) + (size_t)b * NHID;
        #pragma unroll
        for (int c = 0; c < 4; ++c) {
            const int j = c * 256 + tid;
            bool sp = false;
            if (val[c]) {
                float z = __builtin_nontemporal_load(Z0 + zbase + j);
                if (np >= 2)
                    z = __fadd_rn(z, __builtin_nontemporal_load(Z1 + zbase + j));
                if (np >= 3)
                    z = __fadd_rn(z, __builtin_nontemporal_load(Z2 + zbase + j));
                float mm = __fadd_rn(__fadd_rn(__fmul_rn(0.95f, m[c]), z), bj[c]);
                sp = (mm > thr[c]);
                m[c] = sp ? 0.0f : mm;
                __builtin_nontemporal_store(sp ? 1.0f : 0.0f, Sout + sbase + j);
            }
            unsigned long long bits = __ballot(sp);
            if (bm && lane == 0) {
                const int W = c * 4 + wave;
                if (W < 13)
                    bm[((size_t)ct * BATCH + b) * 13 + W] = bits;
            }
        }
    }
    #pragma unroll
    for (int c = 0; c < 4; ++c)
        if (val[c]) mcarry[b * NHID + c * 256 + tid] = m[c];
}

// ---------------------------------------------------------------------------
// Sparse spike GEMM — round-6 proven version (~276 us). Block per row;
// bitmask -> ordered k-list in LDS (popcount prefix), wave-uniform walk.
// Bit-exact: active k appends fadd(part, w); panel folds tracked by k index.
// ---------------------------------------------------------------------------
__global__ __launch_bounds__(256)
void spmm_spikes(const unsigned long long* __restrict__ bm, // [rows][13]
                 const float* __restrict__ W2T,             // [800][800]
                 float* __restrict__ Z,                     // [rows][800]
                 int rows)
{
    __shared__ unsigned long long wbuf[13];
    __shared__ unsigned short list[NHID];
    __shared__ int offs[14];

    const int tid = threadIdx.x;
    const int lane = tid & 63;
    const int wave = tid >> 6;
    const int row = blockIdx.x;

    if (tid < 13) wbuf[tid] = bm[(size_t)row * 13 + tid];
    __syncthreads();
    if (tid == 0) {
        int o = 0;
        for (int w = 0; w < 13; ++w) { offs[w] = o; o += __popcll(wbuf[w]); }
        offs[13] = o;
    }
    __syncthreads();
    for (int W = wave; W < 13; W += 4) {
        const unsigned long long bits = wbuf[W];
        const int pre = __popcll(bits & ((1ull << lane) - 1ull));
        if ((bits >> lane) & 1ull)
            list[offs[W] + pre] = (unsigned short)(W * 64 + lane);
    }
    __syncthreads();
    const int nnz = offs[13];

    if (tid < 200) {
        const int n = 4 * tid;
        float p0 = 0.f, p1 = 0.f, p2 = 0.f, p3 = 0.f;
        float a0 = 0.f, a1 = 0.f, a2 = 0.f, a3 = 0.f;
        int p = 0, nextb = KC;          // 384 then 768 then "never"
        for (int i = 0; i < nnz; ++i) {
            const int k = list[i];
            while (k >= nextb) {
                if (p == 0) { a0 = p0; a1 = p1; a2 = p2; a3 = p3; }
                else {
                    a0 = __fadd_rn(a0, p0); a1 = __fadd_rn(a1, p1);
                    a2 = __fadd_rn(a2, p2); a3 = __fadd_rn(a3, p3);
                }
                p0 = p1 = p2 = p3 = 0.f; ++p;
                nextb = (nextb == KC) ? 2 * KC : 100000;
            }
            const float4 w = *(const float4*)(W2T + (size_t)k * NHID + n);
            p0 = __fadd_rn(p0, w.x); p1 = __fadd_rn(p1, w.y);
            p2 = __fadd_rn(p2, w.z); p3 = __fadd_rn(p3, w.w);
        }
        while (p < 3) {                 // close remaining panels (K=800 -> 3)
            if (p == 0) { a0 = p0; a1 = p1; a2 = p2; a3 = p3; }
            else {
                a0 = __fadd_rn(a0, p0); a1 = __fadd_rn(a1, p1);
                a2 = __fadd_rn(a2, p2); a3 = __fadd_rn(a3, p3);
            }
            p0 = p1 = p2 = p3 = 0.f; ++p;
        }
        *(float4*)(Z + (size_t)row * NHID + n) = make_float4(a0, a1, a2, a3);
    }
}

// ---------------------------------------------------------------------------
// Layer-3 GEMM, float4 loads, chain preserved (folds at float4 idx 96/192).
// ---------------------------------------------------------------------------
__global__ __launch_bounds__(256)
void gemm3_f32(const float* __restrict__ S2, const float* __restrict__ W3,
               float* __restrict__ Z3, int rows)
{
    int gid = blockIdx.x * 256 + threadIdx.x;
    if (gid >= rows * NOUT) return;
    const int m = gid / NOUT;
    const int nn = gid % NOUT;
    const float* a = S2 + (size_t)m * NHID;
    const float* wr = W3 + (size_t)nn * NHID;

    float part = 0.0f, acc = 0.0f;
    int p = 0;
    for (int i = 0; i < NHID / 4; ++i) {
        if (i == 96 || i == 192) {
            acc = (p == 0) ? part : __fadd_rn(acc, part);
            part = 0.0f; ++p;
        }
        const v4f a4 = __builtin_nontemporal_load((const v4f*)(a + 4 * i));
        const float4 w4 = *(const float4*)(wr + 4 * i);
        part = __fmaf_rn(a4.x, w4.x, part);
        part = __fmaf_rn(a4.y, w4.y, part);
        part = __fmaf_rn(a4.z, w4.z, part);
        part = __fmaf_rn(a4.w, w4.w, part);
    }
    acc = (p == 0) ? part : __fadd_rn(acc, part);
    Z3[gid] = acc;
}

// ---------------------------------------------------------------------------
__global__ __launch_bounds__(256)
void lif_scan_small(const float* __restrict__ Z, const float* __restrict__ bias,
                    float* __restrict__ mcarry, float* __restrict__ Sout,
                    int CT, int t0)
{
    const int idx = blockIdx.x * blockDim.x + threadIdx.x;
    const int total = BATCH * NOUT;
    if (idx >= total) return;
    const int j = idx % NOUT;
    const float thr = 1.0f;
    const float bj = bias[j];

    float m = mcarry[idx];
    for (int ct = 0; ct < CT; ++ct) {
        float z = Z[(size_t)ct * total + idx];
        m = __fadd_rn(__fadd_rn(__fmul_rn(0.95f, m), z), bj);
        float s;
        if (m > thr) { s = 1.0f; m = 0.0f; }
        else         { s = 0.0f; }
        Sout[(size_t)(t0 + ct) * total + idx] = s;
    }
    mcarry[idx] = m;
}

// ---------------------------------------------------------------------------
__global__ __launch_bounds__(256)
void sum_t(const float* __restrict__ S3, float* __restrict__ out0)
{
    const int idx = blockIdx.x * blockDim.x + threadIdx.x;
    if (idx >= BATCH * NOUT) return;
    float s = 0.0f;
    for (int t = 0; t < TSTEPS; ++t)
        s += S3[(size_t)t * BATCH * NOUT + idx];
    out0[idx] = s;
}

// ---------------------------------------------------------------------------
extern "C" void kernel_launch(void* const* d_in, const int* in_sizes, int n_in,
                              void* d_out, int out_size, void* d_ws, size_t ws_size,
                              hipStream_t stream)
{
    const float* x       = (const float*)d_in[0];
    const float* W1      = (const float*)d_in[1];
    const float* b1      = (const float*)d_in[2];
    const float* W2      = (const float*)d_in[3];
    const float* b2      = (const float*)d_in[4];
    const float* W3      = (const float*)d_in[5];
    const float* b3      = (const float*)d_in[6];
    const float* budget1 = (const float*)d_in[7];
    const float* budget2 = (const float*)d_in[8];

    float* out  = (float*)d_out;
    float* out0 = out;
    float* out1 = out0 + BATCH * NOUT;
    float* out2 = out1 + (size_t)TSTEPS * BATCH * NHID;
    float* out3 = out2 + (size_t)TSTEPS * BATCH * NHID;

    const size_t nBH = (size_t)BATCH * NHID;     // 409600
    const size_t nBO = (size_t)BATCH * NOUT;     // 5120
    float* m1c = (float*)d_ws;
    float* m2c = m1c + nBH;
    float* m3c = m2c + nBH;
    float* w2t = m3c + nBO;
    unsigned long long* bmask = (unsigned long long*)(w2t + (size_t)NHID * NHID);
    float* Z = (float*)(bmask + (size_t)TSTEPS * BATCH * 13);

    const size_t fixedF = 2 * nBH + nBO + (size_t)NHID * NHID
                        + (size_t)TSTEPS * BATCH * 13 * 2;
    size_t availF = (ws_size / 4 > fixedF) ? (ws_size / 4 - fixedF) : 0;
    // per timestep: 3 Z-panels (layer 1) + Z3
    const size_t perT = (size_t)BATCH * (3 * NHID + NOUT);
    int CT = (int)(availF / perT);
    if (CT > TSTEPS) CT = TSTEPS;
    if (CT < 1) CT = 1;

    hipMemsetAsync(d_ws, 0, (2 * nBH + nBO) * sizeof(float), stream);

    {
        dim3 tg(25, 25);
        transpose800<<<tg, 256, 0, stream>>>(W2, w2t);
    }

    for (int t0 = 0; t0 < TSTEPS; t0 += CT) {
        int ct = TSTEPS - t0 < CT ? TSTEPS - t0 : CT;
        int Mrows = ct * BATCH;
        const size_t pstride = (size_t)ct * BATCH * NHID;
        float* Zp0 = Z;
        float* Zp1 = Z + pstride;
        float* Zp2 = Z + 2 * pstride;
        float* Z3  = Z + 3 * pstride;

        // layer 1: three K-panels of x_chunk @ W1^T
        {
            dim3 grid(Mrows / 128, (NHID + 127) / 128);
            const float* xc = x + (size_t)t0 * BATCH * NIN;
            gemm_panel_f32<<<grid, 256, 0, stream>>>(xc, W1, Zp0, Mrows, NHID, NIN, 0,   384);
            gemm_panel_f32<<<grid, 256, 0, stream>>>(xc, W1, Zp1, Mrows, NHID, NIN, 384, 768);
            gemm_panel_f32<<<grid, 256, 0, stream>>>(xc, W1, Zp2, Mrows, NHID, NIN, 768, 784);
        }
        lif_scan_hid<<<BATCH, 256, 0, stream>>>(
            Zp0, Zp1, Zp2, 3, b1, budget1, m1c, out1, bmask, ct, t0);

        // layer 2: sparse Z = s1_chunk @ W2^T via bitmask (1 row/block)
        spmm_spikes<<<Mrows, 256, 0, stream>>>(bmask, w2t, Zp0, Mrows);
        lif_scan_hid<<<BATCH, 256, 0, stream>>>(
            Zp0, nullptr, nullptr, 1, b2, budget2, m2c, out2, nullptr, ct, t0);

        // layer 3
        gemm3_f32<<<(Mrows * NOUT + 255) / 256, 256, 0, stream>>>(
            out2 + (size_t)t0 * BATCH * NHID, W3, Z3, Mrows);
        lif_scan_small<<<(BATCH * NOUT + 255) / 256, 256, 0, stream>>>(
            Z3, b3, m3c, out3, ct, t0);
    }

    sum_t<<<(BATCH * NOUT + 255) / 256, 256, 0, stream>>>(out3, out0);
}

// Round 14
// 840.362 us; speedup vs baseline: 4.7721x; 1.1974x over previous
//
#include <hip/hip_runtime.h>

#define BATCH   512
#define TSTEPS  50
#define NIN     784
#define NHID    800
#define NOUT    10
#define KC      384   // OpenBLAS SGEMM_DEFAULT_Q — panel folds at k=384, 768

typedef float v4f __attribute__((ext_vector_type(4)));

// ---------------------------------------------------------------------------
// Panel GEMM (NT): ONE KC-panel ascending-k FMA chain per output element.
// 128x128 tile, 8x8 micro, BK=8, k-major LDS, swizzled B.
// Accumulator = 16 NAMED float4 variables (no local array -> SROA can't fail
// -> cannot silently land in scratch; rounds 12/13 showed part[8][8] compiled
// to VGPR=60 + scratch regardless of launch_bounds).
// Requires M%128==0, (ke-ks)%8==0.
// ---------------------------------------------------------------------------
#define ROW_FMA(pl, ph, as)                       \
    pl.x = __fmaf_rn(as, blo.x, pl.x);            \
    pl.y = __fmaf_rn(as, blo.y, pl.y);            \
    pl.z = __fmaf_rn(as, blo.z, pl.z);            \
    pl.w = __fmaf_rn(as, blo.w, pl.w);            \
    ph.x = __fmaf_rn(as, bhi.x, ph.x);            \
    ph.y = __fmaf_rn(as, bhi.y, ph.y);            \
    ph.z = __fmaf_rn(as, bhi.z, ph.z);            \
    ph.w = __fmaf_rn(as, bhi.w, ph.w);

#define STORE_ROW(i, pl, ph)                                        \
    {   float* crow = Cp + (size_t)(m0 + 8*ty + (i)) * N + cb;      \
        if (cb + 4 <= N) *(float4*)crow = pl;                       \
        if (cb + 8 <= N) *(float4*)(crow + 4) = ph; }

__global__ __launch_bounds__(256, 2)
void gemm_panel_f32(const float* __restrict__ A, const float* __restrict__ B,
                    float* __restrict__ Cp, int M, int N, int K,
                    int ks, int ke)
{
    __shared__ float As[8][132];   // [k][m]
    __shared__ float Bs[8][188];   // [k][phys(n)], phys = 12*(n>>3)+(n&7)

    const int tid = threadIdx.x;
    const int tx = tid & 15;        // n micro: 8 cols at 8*tx
    const int ty = tid >> 4;        // m micro: 8 rows at 8*ty
    const int m0 = blockIdx.x * 128;
    const int n0 = blockIdx.y * 128;

    const int srow = tid >> 1;          // 0..127
    const int skq  = (tid & 1) * 4;     // 0 or 4
    const int bphys = 12 * (srow >> 3) + (srow & 7);

    const float* Aptr = A + (size_t)(m0 + srow) * K + skq;
    const float* Bptr = B + (size_t)(n0 + srow) * K + skq;
    const bool bval = (n0 + srow) < N;

    float4 p0l = {0,0,0,0}, p0h = {0,0,0,0}, p1l = {0,0,0,0}, p1h = {0,0,0,0};
    float4 p2l = {0,0,0,0}, p2h = {0,0,0,0}, p3l = {0,0,0,0}, p3h = {0,0,0,0};
    float4 p4l = {0,0,0,0}, p4h = {0,0,0,0}, p5l = {0,0,0,0}, p5h = {0,0,0,0};
    float4 p6l = {0,0,0,0}, p6h = {0,0,0,0}, p7l = {0,0,0,0}, p7h = {0,0,0,0};

    float4 av = *(const float4*)(Aptr + ks);
    float4 bv = bval ? *(const float4*)(Bptr + ks) : make_float4(0.f,0.f,0.f,0.f);

    for (int k0 = ks; k0 < ke; k0 += 8) {
        __syncthreads();
        As[skq+0][srow] = av.x; As[skq+1][srow] = av.y;
        As[skq+2][srow] = av.z; As[skq+3][srow] = av.w;
        Bs[skq+0][bphys] = bv.x; Bs[skq+1][bphys] = bv.y;
        Bs[skq+2][bphys] = bv.z; Bs[skq+3][bphys] = bv.w;
        __syncthreads();

        if (k0 + 8 < ke) {
            av = *(const float4*)(Aptr + k0 + 8);
            bv = bval ? *(const float4*)(Bptr + k0 + 8)
                      : make_float4(0.f,0.f,0.f,0.f);
        }

        #pragma unroll
        for (int kk = 0; kk < 8; ++kk) {
            const float4 alo = *(const float4*)&As[kk][8*ty];
            const float4 ahi = *(const float4*)&As[kk][8*ty + 4];
            const float4 blo = *(const float4*)&Bs[kk][12*tx];
            const float4 bhi = *(const float4*)&Bs[kk][12*tx + 4];
            ROW_FMA(p0l, p0h, alo.x)
            ROW_FMA(p1l, p1h, alo.y)
            ROW_FMA(p2l, p2h, alo.z)
            ROW_FMA(p3l, p3h, alo.w)
            ROW_FMA(p4l, p4h, ahi.x)
            ROW_FMA(p5l, p5h, ahi.y)
            ROW_FMA(p6l, p6h, ahi.z)
            ROW_FMA(p7l, p7h, ahi.w)
        }
    }

    const int cb = n0 + 8 * tx;
    STORE_ROW(0, p0l, p0h)
    STORE_ROW(1, p1l, p1h)
    STORE_ROW(2, p2l, p2h)
    STORE_ROW(3, p3l, p3h)
    STORE_ROW(4, p4l, p4h)
    STORE_ROW(5, p5l, p5h)
    STORE_ROW(6, p6l, p6h)
    STORE_ROW(7, p7l, p7h)
}

// ---------------------------------------------------------------------------
// 800x800 transpose: W2T[k][n] = W2[n][k]
// ---------------------------------------------------------------------------
__global__ __launch_bounds__(256)
void transpose800(const float* __restrict__ W2, float* __restrict__ W2T)
{
    __shared__ float t[32][33];
    const int tx  = threadIdx.x & 31;
    const int ty8 = threadIdx.x >> 5;
    const int bx = blockIdx.x * 32, by = blockIdx.y * 32;

    #pragma unroll
    for (int r = 0; r < 4; ++r) {
        int a = ty8 + r * 8;
        t[a][tx] = W2[(size_t)(by + a) * 800 + bx + tx];
    }
    __syncthreads();
    #pragma unroll
    for (int r = 0; r < 4; ++r) {
        int a = ty8 + r * 8;
        W2T[(size_t)(bx + a) * 800 + by + tx] = t[tx][a];
    }
}

// ---------------------------------------------------------------------------
// Layer-1 LIF scan with fused P3: z = ((P1 + P2) + P3), where P3 is the
// 16-term ascending-k FMA chain over k=768..784 computed here (W1 slice in
// LDS, x slice in regs). Bit-exact OpenBLAS panel combine. Emits bitmask.
// ---------------------------------------------------------------------------
__global__ __launch_bounds__(256)
void lif_scan_hid1(const float* __restrict__ Z0,
                   const float* __restrict__ Z1,
                   const float* __restrict__ xc,   // x + t0*BATCH*NIN
                   const float* __restrict__ W1,
                   const float* __restrict__ bias,
                   const float* __restrict__ budget,
                   float* __restrict__ mcarry,
                   float* __restrict__ Sout,
                   unsigned long long* __restrict__ bm,
                   int CT, int t0)
{
    __shared__ float W1s[NHID][17];   // slice W1[:,768:784], pad 17 (bank spread)

    const int b = blockIdx.x;
    const int tid = threadIdx.x;
    const int lane = tid & 63;
    const int wave = tid >> 6;

    for (int q = tid; q < NHID * 16; q += 256)
        W1s[q >> 4][q & 15] = W1[(size_t)(q >> 4) * NIN + 768 + (q & 15)];
    __syncthreads();

    float m[4], thr[4], bj[4];
    bool val[4];
    int jjv[4];
    #pragma unroll
    for (int c = 0; c < 4; ++c) {
        const int j = c * 256 + tid;
        val[c] = (j < NHID);
        const int jj = val[c] ? j : 0;
        jjv[c] = jj;
        float bu = budget[jj];
        bu = fminf(fmaxf(bu, 0.01f), 1.0f);
        thr[c] = __fdiv_rn(1.0f, bu);
        bj[c]  = bias[jj];
        m[c]   = mcarry[b * NHID + jj];
    }

    for (int ct = 0; ct < CT; ++ct) {
        const size_t zbase = (size_t)ct * (BATCH * NHID) + (size_t)b * NHID;
        const size_t sbase = (size_t)(t0 + ct) * (BATCH * NHID) + (size_t)b * NHID;
        const float* xr = xc + ((size_t)ct * BATCH + b) * NIN + 768;
        const float4 x0 = *(const float4*)(xr);
        const float4 x1 = *(const float4*)(xr + 4);
        const float4 x2 = *(const float4*)(xr + 8);
        const float4 x3 = *(const float4*)(xr + 12);

        #pragma unroll
        for (int c = 0; c < 4; ++c) {
            const int j = c * 256 + tid;
            bool sp = false;
            if (val[c]) {
                const int jj = jjv[c];
                float z = __fadd_rn(__builtin_nontemporal_load(Z0 + zbase + j),
                                    __builtin_nontemporal_load(Z1 + zbase + j));
                float p3 = 0.0f;
                p3 = __fmaf_rn(x0.x, W1s[jj][0],  p3);
                p3 = __fmaf_rn(x0.y, W1s[jj][1],  p3);
                p3 = __fmaf_rn(x0.z, W1s[jj][2],  p3);
                p3 = __fmaf_rn(x0.w, W1s[jj][3],  p3);
                p3 = __fmaf_rn(x1.x, W1s[jj][4],  p3);
                p3 = __fmaf_rn(x1.y, W1s[jj][5],  p3);
                p3 = __fmaf_rn(x1.z, W1s[jj][6],  p3);
                p3 = __fmaf_rn(x1.w, W1s[jj][7],  p3);
                p3 = __fmaf_rn(x2.x, W1s[jj][8],  p3);
                p3 = __fmaf_rn(x2.y, W1s[jj][9],  p3);
                p3 = __fmaf_rn(x2.z, W1s[jj][10], p3);
                p3 = __fmaf_rn(x2.w, W1s[jj][11], p3);
                p3 = __fmaf_rn(x3.x, W1s[jj][12], p3);
                p3 = __fmaf_rn(x3.y, W1s[jj][13], p3);
                p3 = __fmaf_rn(x3.z, W1s[jj][14], p3);
                p3 = __fmaf_rn(x3.w, W1s[jj][15], p3);
                z = __fadd_rn(z, p3);

                float mm = __fadd_rn(__fadd_rn(__fmul_rn(0.95f, m[c]), z), bj[c]);
                sp = (mm > thr[c]);
                m[c] = sp ? 0.0f : mm;
                __builtin_nontemporal_store(sp ? 1.0f : 0.0f, Sout + sbase + j);
            }
            unsigned long long bits = __ballot(sp);
            if (lane == 0) {
                const int W = c * 4 + wave;
                if (W < 13)
                    bm[((size_t)ct * BATCH + b) * 13 + W] = bits;
            }
        }
    }
    #pragma unroll
    for (int c = 0; c < 4; ++c)
        if (val[c]) mcarry[b * NHID + c * 256 + tid] = m[c];
}

// ---------------------------------------------------------------------------
// Layer-2 LIF scan (single-panel z), no bitmask.
// ---------------------------------------------------------------------------
__global__ __launch_bounds__(256)
void lif_scan_hid2(const float* __restrict__ Z0,
                   const float* __restrict__ bias,
                   const float* __restrict__ budget,
                   float* __restrict__ mcarry,
                   float* __restrict__ Sout,
                   int CT, int t0)
{
    const int b = blockIdx.x;
    const int tid = threadIdx.x;

    float m[4], thr[4], bj[4];
    bool val[4];
    #pragma unroll
    for (int c = 0; c < 4; ++c) {
        const int j = c * 256 + tid;
        val[c] = (j < NHID);
        const int jj = val[c] ? j : 0;
        float bu = budget[jj];
        bu = fminf(fmaxf(bu, 0.01f), 1.0f);
        thr[c] = __fdiv_rn(1.0f, bu);
        bj[c]  = bias[jj];
        m[c]   = mcarry[b * NHID + jj];
    }

    for (int ct = 0; ct < CT; ++ct) {
        const size_t zbase = (size_t)ct * (BATCH * NHID) + (size_t)b * NHID;
        const size_t sbase = (size_t)(t0 + ct) * (BATCH * NHID) + (size_t)b * NHID;
        #pragma unroll
        for (int c = 0; c < 4; ++c) {
            const int j = c * 256 + tid;
            if (val[c]) {
                float z = __builtin_nontemporal_load(Z0 + zbase + j);
                float mm = __fadd_rn(__fadd_rn(__fmul_rn(0.95f, m[c]), z), bj[c]);
                bool sp = (mm > thr[c]);
                m[c] = sp ? 0.0f : mm;
                __builtin_nontemporal_store(sp ? 1.0f : 0.0f, Sout + sbase + j);
            }
        }
    }
    #pragma unroll
    for (int c = 0; c < 4; ++c)
        if (val[c]) mcarry[b * NHID + c * 256 + tid] = m[c];
}

// ---------------------------------------------------------------------------
// Sparse spike GEMM — round-6 proven version. Block per row; bitmask ->
// ordered k-list in LDS, wave-uniform walk; folds tracked by k index.
// ---------------------------------------------------------------------------
__global__ __launch_bounds__(256)
void spmm_spikes(const unsigned long long* __restrict__ bm, // [rows][13]
                 const float* __restrict__ W2T,             // [800][800]
                 float* __restrict__ Z,                     // [rows][800]
                 int rows)
{
    __shared__ unsigned long long wbuf[13];
    __shared__ unsigned short list[NHID];
    __shared__ int offs[14];

    const int tid = threadIdx.x;
    const int lane = tid & 63;
    const int wave = tid >> 6;
    const int row = blockIdx.x;

    if (tid < 13) wbuf[tid] = bm[(size_t)row * 13 + tid];
    __syncthreads();
    if (tid == 0) {
        int o = 0;
        for (int w = 0; w < 13; ++w) { offs[w] = o; o += __popcll(wbuf[w]); }
        offs[13] = o;
    }
    __syncthreads();
    for (int W = wave; W < 13; W += 4) {
        const unsigned long long bits = wbuf[W];
        const int pre = __popcll(bits & ((1ull << lane) - 1ull));
        if ((bits >> lane) & 1ull)
            list[offs[W] + pre] = (unsigned short)(W * 64 + lane);
    }
    __syncthreads();
    const int nnz = offs[13];

    if (tid < 200) {
        const int n = 4 * tid;
        float p0 = 0.f, p1 = 0.f, p2 = 0.f, p3 = 0.f;
        float a0 = 0.f, a1 = 0.f, a2 = 0.f, a3 = 0.f;
        int p = 0, nextb = KC;          // 384 then 768 then "never"
        for (int i = 0; i < nnz; ++i) {
            const int k = list[i];
            while (k >= nextb) {
                if (p == 0) { a0 = p0; a1 = p1; a2 = p2; a3 = p3; }
                else {
                    a0 = __fadd_rn(a0, p0); a1 = __fadd_rn(a1, p1);
                    a2 = __fadd_rn(a2, p2); a3 = __fadd_rn(a3, p3);
                }
                p0 = p1 = p2 = p3 = 0.f; ++p;
                nextb = (nextb == KC) ? 2 * KC : 100000;
            }
            const float4 w = *(const float4*)(W2T + (size_t)k * NHID + n);
            p0 = __fadd_rn(p0, w.x); p1 = __fadd_rn(p1, w.y);
            p2 = __fadd_rn(p2, w.z); p3 = __fadd_rn(p3, w.w);
        }
        while (p < 3) {                 // close remaining panels (K=800 -> 3)
            if (p == 0) { a0 = p0; a1 = p1; a2 = p2; a3 = p3; }
            else {
                a0 = __fadd_rn(a0, p0); a1 = __fadd_rn(a1, p1);
                a2 = __fadd_rn(a2, p2); a3 = __fadd_rn(a3, p3);
            }
            p0 = p1 = p2 = p3 = 0.f; ++p;
        }
        *(float4*)(Z + (size_t)row * NHID + n) = make_float4(a0, a1, a2, a3);
    }
}

// ---------------------------------------------------------------------------
// Layer-3 GEMM, float4 loads, chain preserved (folds at float4 idx 96/192).
// ---------------------------------------------------------------------------
__global__ __launch_bounds__(256)
void gemm3_f32(const float* __restrict__ S2, const float* __restrict__ W3,
               float* __restrict__ Z3, int rows)
{
    int gid = blockIdx.x * 256 + threadIdx.x;
    if (gid >= rows * NOUT) return;
    const int m = gid / NOUT;
    const int nn = gid % NOUT;
    const float* a = S2 + (size_t)m * NHID;
    const float* wr = W3 + (size_t)nn * NHID;

    float part = 0.0f, acc = 0.0f;
    int p = 0;
    for (int i = 0; i < NHID / 4; ++i) {
        if (i == 96 || i == 192) {
            acc = (p == 0) ? part : __fadd_rn(acc, part);
            part = 0.0f; ++p;
        }
        const v4f a4 = __builtin_nontemporal_load((const v4f*)(a + 4 * i));
        const float4 w4 = *(const float4*)(wr + 4 * i);
        part = __fmaf_rn(a4.x, w4.x, part);
        part = __fmaf_rn(a4.y, w4.y, part);
        part = __fmaf_rn(a4.z, w4.z, part);
        part = __fmaf_rn(a4.w, w4.w, part);
    }
    acc = (p == 0) ? part : __fadd_rn(acc, part);
    Z3[gid] = acc;
}

// ---------------------------------------------------------------------------
__global__ __launch_bounds__(256)
void lif_scan_small(const float* __restrict__ Z, const float* __restrict__ bias,
                    float* __restrict__ mcarry, float* __restrict__ Sout,
                    int CT, int t0)
{
    const int idx = blockIdx.x * blockDim.x + threadIdx.x;
    const int total = BATCH * NOUT;
    if (idx >= total) return;
    const int j = idx % NOUT;
    const float thr = 1.0f;
    const float bj = bias[j];

    float m = mcarry[idx];
    for (int ct = 0; ct < CT; ++ct) {
        float z = Z[(size_t)ct * total + idx];
        m = __fadd_rn(__fadd_rn(__fmul_rn(0.95f, m), z), bj);
        float s;
        if (m > thr) { s = 1.0f; m = 0.0f; }
        else         { s = 0.0f; }
        Sout[(size_t)(t0 + ct) * total + idx] = s;
    }
    mcarry[idx] = m;
}

// ---------------------------------------------------------------------------
__global__ __launch_bounds__(256)
void sum_t(const float* __restrict__ S3, float* __restrict__ out0)
{
    const int idx = blockIdx.x * blockDim.x + threadIdx.x;
    if (idx >= BATCH * NOUT) return;
    float s = 0.0f;
    for (int t = 0; t < TSTEPS; ++t)
        s += S3[(size_t)t * BATCH * NOUT + idx];
    out0[idx] = s;
}

// ---------------------------------------------------------------------------
extern "C" void kernel_launch(void* const* d_in, const int* in_sizes, int n_in,
                              void* d_out, int out_size, void* d_ws, size_t ws_size,
                              hipStream_t stream)
{
    const float* x       = (const float*)d_in[0];
    const float* W1      = (const float*)d_in[1];
    const float* b1      = (const float*)d_in[2];
    const float* W2      = (const float*)d_in[3];
    const float* b2      = (const float*)d_in[4];
    const float* W3      = (const float*)d_in[5];
    const float* b3      = (const float*)d_in[6];
    const float* budget1 = (const float*)d_in[7];
    const float* budget2 = (const float*)d_in[8];

    float* out  = (float*)d_out;
    float* out0 = out;
    float* out1 = out0 + BATCH * NOUT;
    float* out2 = out1 + (size_t)TSTEPS * BATCH * NHID;
    float* out3 = out2 + (size_t)TSTEPS * BATCH * NHID;

    const size_t nBH = (size_t)BATCH * NHID;     // 409600
    const size_t nBO = (size_t)BATCH * NOUT;     // 5120
    float* m1c = (float*)d_ws;
    float* m2c = m1c + nBH;
    float* m3c = m2c + nBH;
    float* w2t = m3c + nBO;
    unsigned long long* bmask = (unsigned long long*)(w2t + (size_t)NHID * NHID);
    float* Z = (float*)(bmask + (size_t)TSTEPS * BATCH * 13);

    const size_t fixedF = 2 * nBH + nBO + (size_t)NHID * NHID
                        + (size_t)TSTEPS * BATCH * 13 * 2;
    size_t availF = (ws_size / 4 > fixedF) ? (ws_size / 4 - fixedF) : 0;
    // per timestep: 2 Z-panels (layer 1) + Z3
    const size_t perT = (size_t)BATCH * (2 * NHID + NOUT);
    int CT = (int)(availF / perT);
    if (CT > TSTEPS) CT = TSTEPS;
    if (CT < 1) CT = 1;

    hipMemsetAsync(d_ws, 0, (2 * nBH + nBO) * sizeof(float), stream);

    {
        dim3 tg(25, 25);
        transpose800<<<tg, 256, 0, stream>>>(W2, w2t);
    }

    for (int t0 = 0; t0 < TSTEPS; t0 += CT) {
        int ct = TSTEPS - t0 < CT ? TSTEPS - t0 : CT;
        int Mrows = ct * BATCH;
        const size_t pstride = (size_t)ct * BATCH * NHID;
        float* Zp0 = Z;
        float* Zp1 = Z + pstride;
        float* Z3  = Z + 2 * pstride;
        const float* xc = x + (size_t)t0 * BATCH * NIN;

        // layer 1: two K-panels of x_chunk @ W1^T (P3 fused into lif)
        {
            dim3 grid(Mrows / 128, (NHID + 127) / 128);
            gemm_panel_f32<<<grid, 256, 0, stream>>>(xc, W1, Zp0, Mrows, NHID, NIN, 0,   384);
            gemm_panel_f32<<<grid, 256, 0, stream>>>(xc, W1, Zp1, Mrows, NHID, NIN, 384, 768);
        }
        lif_scan_hid1<<<BATCH, 256, 0, stream>>>(
            Zp0, Zp1, xc, W1, b1, budget1, m1c, out1, bmask, ct, t0);

        // layer 2: sparse Z = s1_chunk @ W2^T via bitmask (1 row/block)
        spmm_spikes<<<Mrows, 256, 0, stream>>>(bmask, w2t, Zp0, Mrows);
        lif_scan_hid2<<<BATCH, 256, 0, stream>>>(
            Zp0, b2, budget2, m2c, out2, ct, t0);

        // layer 3
        gemm3_f32<<<(Mrows * NOUT + 255) / 256, 256, 0, stream>>>(
            out2 + (size_t)t0 * BATCH * NHID, W3, Z3, Mrows);
        lif_scan_small<<<(BATCH * NOUT + 255) / 256, 256, 0, stream>>>(
            Z3, b3, m3c, out3, ct, t0);
    }

    sum_t<<<(BATCH * NOUT + 255) / 256, 256, 0, stream>>>(out3, out0);
}